// Round 1
// baseline (377.478 us; speedup 1.0000x reference)
//
#include <hip/hip_runtime.h>
#include <stdint.h>

#define NPIX 4096
#define CDIM 512
#define NGRP 32

typedef _Float16 hv8 __attribute__((ext_vector_type(8)));
typedef float f32x4 __attribute__((ext_vector_type(4)));

__device__ __forceinline__ void lds_direct16(const _Float16* g, _Float16* l) {
    __builtin_amdgcn_global_load_lds(
        (const __attribute__((address_space(1))) void*)g,
        (__attribute__((address_space(3))) void*)l, 16, 0, 0);
}

// ---------------- weight fp32 -> fp16 ----------------
__global__ void cvt_w(const float* __restrict__ s0, const float* __restrict__ s1,
                      const float* __restrict__ s2, const float* __restrict__ s3,
                      _Float16* __restrict__ d0, _Float16* __restrict__ d1,
                      _Float16* __restrict__ d2, _Float16* __restrict__ d3) {
    int i = blockIdx.x * 256 + threadIdx.x;
    d0[i] = (_Float16)s0[i];
    d1[i] = (_Float16)s1[i];
    d2[i] = (_Float16)s2[i];
    d3[i] = (_Float16)s3[i];
}

// ---------------- groupnorm stats: one block per (b,g) ----------------
__global__ void stats_kernel(const float* __restrict__ x, float* __restrict__ stats) {
    int idx = blockIdx.x;                      // b*32+g ; group base is contiguous
    const float4* base = (const float4*)(x + (long)idx * 16 * NPIX);
    int tid = threadIdx.x;
    float s = 0.f, sq = 0.f;
    for (int it = 0; it < 64; ++it) {
        float4 f = base[it * 256 + tid];
        s  += f.x + f.y + f.z + f.w;
        sq += f.x * f.x + f.y * f.y + f.z * f.z + f.w * f.w;
    }
    __shared__ float rs[256], rq[256];
    rs[tid] = s; rq[tid] = sq;
    __syncthreads();
    for (int st = 128; st > 0; st >>= 1) {
        if (tid < st) { rs[tid] += rs[tid + st]; rq[tid] += rq[tid + st]; }
        __syncthreads();
    }
    if (tid == 0) {
        float mean = rs[0] * (1.0f / 65536.0f);
        float var  = rq[0] * (1.0f / 65536.0f) - mean * mean;
        stats[idx * 2]     = mean;
        stats[idx * 2 + 1] = rsqrtf(var + 1e-6f);
    }
}

// ---------------- normalize + transpose: hT[b][n][c] = GN(x)[b][c][n] ----------------
__global__ void normT_kernel(const float* __restrict__ x, const float* __restrict__ stats,
                             const float* __restrict__ gamma, const float* __restrict__ beta,
                             _Float16* __restrict__ hT) {
    int b = blockIdx.z, c0 = blockIdx.x * 32, n0 = blockIdx.y * 32;
    int tid = threadIdx.x;
    __shared__ float t[32][33];
    int cl = tid >> 5;     // 0..7
    int nl = tid & 31;
    for (int r = 0; r < 4; ++r)
        t[r * 8 + cl][nl] = x[(long)b * CDIM * NPIX + (long)(c0 + r * 8 + cl) * NPIX + n0 + nl];
    __syncthreads();
    for (int r = 0; r < 4; ++r) {
        int nr = r * 8 + cl;
        int c = c0 + nl;
        float m    = stats[(b * 32 + (c >> 4)) * 2];
        float rstd = stats[(b * 32 + (c >> 4)) * 2 + 1];
        float val = (t[nl][nr] - m) * rstd * gamma[c] + beta[c];
        hT[(long)b * NPIX * CDIM + (long)(n0 + nr) * CDIM + c] = (_Float16)val;
    }
}

// ---------------- bt-form GEMM: D[M][N] = A[M][K] * BT[N][K]^T ----------------
// EPI 0: fp16 store, bias indexed by col
// EPI 1: fp16 store, bias indexed by row
// EPI 2: fp32 store, bias row + residual add
template<int EPI>
__launch_bounds__(256, 2)
__global__ void gemm_bt_kernel(const _Float16* __restrict__ A, const _Float16* __restrict__ BT,
                               void* __restrict__ D, const float* __restrict__ bias,
                               const float* __restrict__ resid,
                               int M, int N, int K,
                               long aBatch, long bBatch, long dBatch, long rBatch) {
    const int b = blockIdx.z;
    A  += (long)b * aBatch;
    BT += (long)b * bBatch;
    const int m0 = blockIdx.y * 128;
    const int n0 = blockIdx.x * 128;
    const int tid = threadIdx.x;
    const int l = tid & 63;
    const int w = tid >> 6;
    const int wm = (w >> 1) * 64;
    const int wn = (w & 1) * 64;
    const int lr = l & 15;
    const int lk = l >> 4;
    __shared__ __align__(16) _Float16 As[128 * 32];
    __shared__ __align__(16) _Float16 Bs[128 * 32];
    f32x4 acc[4][4] = {};
    const int nK = K >> 5;
    for (int kt = 0; kt < nK; ++kt) {
        const int kb = kt * 32;
#pragma unroll
        for (int c = 0; c < 2; ++c) {
            int chunk = c * 256 + tid;
            int row = chunk >> 2;
            int k8 = (chunk & 3) * 8;
            _Float16* ldsA = As + (size_t)(c * 256 + (tid & ~63)) * 8;
            _Float16* ldsB = Bs + (size_t)(c * 256 + (tid & ~63)) * 8;
            lds_direct16(A  + (long)(m0 + row) * K + kb + k8, ldsA);
            lds_direct16(BT + (long)(n0 + row) * K + kb + k8, ldsB);
        }
        __syncthreads();
        hv8 af[4], bfr[4];
#pragma unroll
        for (int mi = 0; mi < 4; ++mi)
            af[mi] = *(const hv8*)(As + (size_t)(wm + mi * 16 + lr) * 32 + lk * 8);
#pragma unroll
        for (int ni = 0; ni < 4; ++ni)
            bfr[ni] = *(const hv8*)(Bs + (size_t)(wn + ni * 16 + lr) * 32 + lk * 8);
#pragma unroll
        for (int mi = 0; mi < 4; ++mi)
#pragma unroll
            for (int ni = 0; ni < 4; ++ni)
                acc[mi][ni] = __builtin_amdgcn_mfma_f32_16x16x32_f16(af[mi], bfr[ni], acc[mi][ni], 0, 0, 0);
        __syncthreads();
    }
    // epilogue
#pragma unroll
    for (int mi = 0; mi < 4; ++mi)
#pragma unroll
        for (int ni = 0; ni < 4; ++ni)
#pragma unroll
            for (int r = 0; r < 4; ++r) {
                int row = m0 + wm + mi * 16 + lk * 4 + r;
                int col = n0 + wn + ni * 16 + lr;
                float val = acc[mi][ni][r];
                if (EPI == 0) {
                    ((_Float16*)D)[(long)b * dBatch + (long)row * N + col] = (_Float16)(val + bias[col]);
                } else if (EPI == 1) {
                    ((_Float16*)D)[(long)b * dBatch + (long)row * N + col] = (_Float16)(val + bias[row]);
                } else {
                    long idx = (long)row * N + col;
                    ((float*)D)[(long)b * dBatch + idx] =
                        val + bias[row] + resid[(long)b * rBatch + idx];
                }
            }
}

// ---------------- flash attention: qT,kT [N][C], v [C][N] -> oT [N][C] ----------------
__launch_bounds__(512, 1)
__global__ void attn_kernel(const _Float16* __restrict__ qT, const _Float16* __restrict__ kT,
                            const _Float16* __restrict__ v, _Float16* __restrict__ oT) {
    const int b = blockIdx.y;
    const int i0 = blockIdx.x * 32;
    const int tid = threadIdx.x;
    const int l = tid & 63, w = tid >> 6;
    const int lr = l & 15, lk = l >> 4;
    const _Float16* qb = qT + (long)b * NPIX * CDIM;
    const _Float16* kb = kT + (long)b * NPIX * CDIM;
    const _Float16* vb = v  + (long)b * CDIM * NPIX;
    __shared__ __align__(16) _Float16 qs[32 * 512];   // swizzled
    __shared__ __align__(16) _Float16 ps[32 * 128];   // swizzled
    __shared__ float red[8 * 32];
    __shared__ float redt[32];

    // load q tile (32 rows x 512) into LDS with XOR swizzle
    for (int it = 0; it < 4; ++it) {
        int chunk = it * 512 + tid;          // 2048 chunks of 16B
        int row = chunk >> 6;
        int cb = (chunk & 63) * 16;          // byte in row
        uint32_t off = (uint32_t)(row * 1024 + cb) ^ (uint32_t)((row & 7) << 4);
        *(f32x4*)((char*)qs + off) =
            *(const f32x4*)((const char*)qb + (long)(i0 + row) * 1024 + cb);
    }
    __syncthreads();

    f32x4 oacc[2][4] = {};
    float lsum[8] = {};
    const float scale = 0.044194173824159216f;   // 1/sqrt(512)

    for (int jt = 0; jt < 32; ++jt) {
        // ---- S = q * k^T for this wave's 16 j columns ----
        const int jrow = jt * 128 + w * 16 + lr;
        const _Float16* kr = kb + (long)jrow * CDIM;
        f32x4 s[2] = {};
#pragma unroll
        for (int kk = 0; kk < 16; ++kk) {
            hv8 bfr = *(const hv8*)(kr + kk * 32 + lk * 8);
#pragma unroll
            for (int mi = 0; mi < 2; ++mi) {
                int row = mi * 16 + lr;
                uint32_t off = (uint32_t)(row * 1024 + kk * 64 + lk * 16) ^ (uint32_t)((row & 7) << 4);
                hv8 af = *(const hv8*)((const char*)qs + off);
                s[mi] = __builtin_amdgcn_mfma_f32_16x16x32_f16(af, bfr, s[mi], 0, 0, 0);
            }
        }
        // ---- exp + write P (previous PV finished at last barrier) ----
#pragma unroll
        for (int mi = 0; mi < 2; ++mi)
#pragma unroll
            for (int r = 0; r < 4; ++r) {
                float p = __expf(s[mi][r] * scale);
                lsum[mi * 4 + r] += p;
                int row = lk * 4 + r + mi * 16;
                int col = w * 16 + lr;
                uint32_t off = (uint32_t)(row * 256 + col * 2) ^ (uint32_t)((row & 7) << 4);
                *(_Float16*)((char*)ps + off) = (_Float16)p;
            }
        __syncthreads();
        // ---- PV: oT_acc += P * v^T(bt) ----
        const int jb = jt * 128;
#pragma unroll
        for (int ks = 0; ks < 4; ++ks) {
            hv8 pa[2];
#pragma unroll
            for (int mi = 0; mi < 2; ++mi) {
                int row = mi * 16 + lr;
                uint32_t off = (uint32_t)(row * 256 + ks * 64 + lk * 16) ^ (uint32_t)((row & 7) << 4);
                pa[mi] = *(const hv8*)((const char*)ps + off);
            }
#pragma unroll
            for (int ni = 0; ni < 4; ++ni) {
                int c = w * 64 + ni * 16 + lr;
                hv8 vf = *(const hv8*)(vb + (long)c * NPIX + jb + ks * 32 + lk * 8);
#pragma unroll
                for (int mi = 0; mi < 2; ++mi)
                    oacc[mi][ni] = __builtin_amdgcn_mfma_f32_16x16x32_f16(pa[mi], vf, oacc[mi][ni], 0, 0, 0);
            }
        }
        __syncthreads();
    }

    // ---- reduce row sums: across 16 lanes, then across 8 waves ----
#pragma unroll
    for (int m = 1; m <= 8; m <<= 1)
#pragma unroll
        for (int i = 0; i < 8; ++i)
            lsum[i] += __shfl_xor(lsum[i], m, 64);
    if (lr == 0) {
#pragma unroll
        for (int i = 0; i < 8; ++i) {
            int row = lk * 4 + (i & 3) + (i >> 2) * 16;
            red[w * 32 + row] = lsum[i];
        }
    }
    __syncthreads();
    if (tid < 32) {
        float t = 0.f;
#pragma unroll
        for (int ww = 0; ww < 8; ++ww) t += red[ww * 32 + tid];
        redt[tid] = 1.0f / t;
    }
    __syncthreads();
    float rinv[8];
#pragma unroll
    for (int i = 0; i < 8; ++i)
        rinv[i] = redt[lk * 4 + (i & 3) + (i >> 2) * 16];

    _Float16* ob = oT + (long)b * NPIX * CDIM;
#pragma unroll
    for (int mi = 0; mi < 2; ++mi)
#pragma unroll
        for (int ni = 0; ni < 4; ++ni)
#pragma unroll
            for (int r = 0; r < 4; ++r) {
                int row = i0 + lk * 4 + r + mi * 16;
                int c = w * 64 + ni * 16 + lr;
                ob[(long)row * CDIM + c] = (_Float16)(oacc[mi][ni][r] * rinv[mi * 4 + r]);
            }
}

extern "C" void kernel_launch(void* const* d_in, const int* in_sizes, int n_in,
                              void* d_out, int out_size, void* d_ws, size_t ws_size,
                              hipStream_t stream) {
    const float* x     = (const float*)d_in[0];
    const float* gamma = (const float*)d_in[1];
    const float* beta  = (const float*)d_in[2];
    const float* wq    = (const float*)d_in[3];
    const float* bq    = (const float*)d_in[4];
    const float* wk    = (const float*)d_in[5];
    const float* bk    = (const float*)d_in[6];
    const float* wv    = (const float*)d_in[7];
    const float* bv    = (const float*)d_in[8];
    const float* wo    = (const float*)d_in[9];
    const float* bo    = (const float*)d_in[10];
    float* out = (float*)d_out;

    char* ws = (char*)d_ws;
    float* stats = (float*)ws;                       // 128 floats
    _Float16* wqb = (_Float16*)(ws + 1024);
    _Float16* wkb = wqb + 262144;
    _Float16* wvb = wkb + 262144;
    _Float16* wob = wvb + 262144;
    _Float16* hT  = wob + 262144;                    // [B][N][C]
    const long TSZ = (long)2 * NPIX * CDIM;
    _Float16* qT = hT + TSZ;                         // [B][N][C]
    _Float16* kT = qT + TSZ;                         // [B][N][C]
    _Float16* vv = kT + TSZ;                         // [B][C][N]
    _Float16* oT = vv + TSZ;                         // [B][N][C]

    cvt_w<<<dim3(1024), dim3(256), 0, stream>>>(wq, wk, wv, wo, wqb, wkb, wvb, wob);
    stats_kernel<<<dim3(64), dim3(256), 0, stream>>>(x, stats);
    normT_kernel<<<dim3(16, 128, 2), dim3(256), 0, stream>>>(x, stats, gamma, beta, hT);

    const long NC = (long)NPIX * CDIM;
    // qT = hT *bt wq  (M=4096, N=512, K=512)
    gemm_bt_kernel<0><<<dim3(4, 32, 2), dim3(256), 0, stream>>>(
        hT, wqb, (void*)qT, bq, nullptr, NPIX, CDIM, CDIM, NC, 0L, NC, 0L);
    gemm_bt_kernel<0><<<dim3(4, 32, 2), dim3(256), 0, stream>>>(
        hT, wkb, (void*)kT, bk, nullptr, NPIX, CDIM, CDIM, NC, 0L, NC, 0L);
    // v = wv *bt hT   (M=512, N=4096, K=512)
    gemm_bt_kernel<1><<<dim3(32, 4, 2), dim3(256), 0, stream>>>(
        wvb, hT, (void*)vv, bv, nullptr, CDIM, NPIX, CDIM, 0L, NC, NC, 0L);

    attn_kernel<<<dim3(128, 2), dim3(512), 0, stream>>>(qT, kT, vv, oT);

    // out = wo *bt oT + bo + x  (fp32, M=512, N=4096)
    gemm_bt_kernel<2><<<dim3(32, 4, 2), dim3(256), 0, stream>>>(
        wob, oT, (void*)out, bo, x, CDIM, NPIX, CDIM, 0L, NC, NC, NC);
}